// Round 19
// baseline (81.542 us; speedup 1.0000x reference)
//
#include <hip/hip_runtime.h>
#include <math.h>

#define N_NODES 50000
#define N_EDGES 800000
#define IN_F 128
#define OUT_F 64

#define NBUK 196        // col>>8 buckets (ceil(50000/256))
#define BCAP 5120       // slab capacity per bucket (mean 4082, sigma 64 -> +16 sigma)
#define BIN_CHUNK 2048  // edges per bin block
#define BIN_BLOCKS ((N_EDGES + BIN_CHUNK - 1) / BIN_CHUNK)  // 391
#define QK_NB 64        // nodes per block in the qk path
#define QK_BLOCKS ((N_NODES + QK_NB - 1) / QK_NB)           // 782

typedef __attribute__((ext_vector_type(8))) short short8v;  // 8 bf16 (4 VGPR)
typedef __attribute__((ext_vector_type(4))) float f32x4;    // MFMA C/D

// ---- RNE f32 -> bf16 helpers (no NaN/inf in this data) ----
__device__ __forceinline__ unsigned short bf16_rne(float f) {
    unsigned u = __float_as_uint(f);
    return (unsigned short)((u + 0x7FFFu + ((u >> 16) & 1u)) >> 16);
}
__device__ __forceinline__ void split2(float f, unsigned short& h, unsigned short& l) {
    h = bf16_rne(f);
    float fh = __uint_as_float(((unsigned)h) << 16);
    l = bf16_rne(f - fh);
}
__device__ __forceinline__ float bf2f(ushort h) {
    return __uint_as_float(((unsigned)h) << 16);
}

// Split Wq and Wk into bf16 hi/lo pairs. Also zeroes bcnt, seeds offs[N_NODES],
// and computes the int64-vs-int32 edge-layout flag ONCE. Runs FIRST.
__global__ __launch_bounds__(256) void wsplit(const float* __restrict__ Wq,
                                              const float* __restrict__ Wk,
                                              const int* __restrict__ ei,
                                              ushort* __restrict__ wh,
                                              ushort* __restrict__ wl,
                                              int* __restrict__ bcnt,
                                              int* __restrict__ offs,
                                              int* __restrict__ eflag) {
    int i = blockIdx.x * 256 + threadIdx.x;
    if (blockIdx.x == 0 && threadIdx.x < NBUK) bcnt[threadIdx.x] = 0;
    if (blockIdx.x == 0 && threadIdx.x == 0) {
        offs[N_NODES] = N_EDGES;
        int allz = 1;
        for (int k = 0; k < 32; ++k)
            if (ei[2 * k + 1] != 0) allz = 0;
        *eflag = allz;  // 1 => int64 layout (odd words of int64 values < 2^31 are 0)
    }
    if (i >= 2 * OUT_F * IN_F) return;
    float f = (i < OUT_F * IN_F) ? Wq[i] : Wk[i - OUT_F * IN_F];
    unsigned short h, l;
    split2(f, h, l);
    wh[i] = h;
    wl[i] = l;
}

// One matrix's worth of the split-bf16 MFMA GEMM (D = xh*wh + xh*wl + xl*wh,
// xl*wl ~ 2^-18 dropped). Stages ONE matrix's hi/lo planes (32KB) in LDS with
// the XOR swizzle byte^=((j&7)<<4) (wave's 64 b128 reads tile all 32 banks).
// LDS-staged proven vs direct-global in R13/R14 A/B (+15us L1 thrash).
__device__ __forceinline__ void qk_gemm_half(const float* __restrict__ x,
                                             const ushort* __restrict__ whm,
                                             const ushort* __restrict__ wlm,
                                             ushort* __restrict__ Oh,
                                             char* lds0, int qbid, int t) {
    // stage 2 planes (hi, lo) = 2048 b128 units, coalesced reads, swizzled writes
    for (int u = t; u < 2048; u += 256) {
        int hl = u >> 10;
        int j = (u >> 4) & 63;
        int kb = u & 15;
        const ushort* src = hl ? wlm : whm;
        short8v v = *(const short8v*)(src + (j << 7) + (kb << 3));
        unsigned byte = ((unsigned)u * 16u) ^ (((unsigned)j & 7u) << 4);
        *(short8v*)(lds0 + byte) = v;
    }

    const int w = t >> 6, l = t & 63;
    const int base = qbid * QK_NB + w * 16;
    const int lr = l & 15, kg = l >> 4;

    int nodeA = base + lr;
    if (nodeA >= N_NODES) nodeA = N_NODES - 1;  // clamped load, stores guarded
    const float* xp = x + (size_t)nodeA * IN_F + kg * 8;

    short8v ah[4], al[4];
#pragma unroll
    for (int ks = 0; ks < 4; ++ks) {
        float4 a0 = *(const float4*)(xp + ks * 32);
        float4 a1 = *(const float4*)(xp + ks * 32 + 4);
        float v[8] = {a0.x, a0.y, a0.z, a0.w, a1.x, a1.y, a1.z, a1.w};
#pragma unroll
        for (int jj = 0; jj < 8; ++jj) {
            unsigned short h, lo;
            split2(v[jj], h, lo);
            ah[ks][jj] = (short)h;
            al[ks][jj] = (short)lo;
        }
    }

    __syncthreads();

#pragma unroll
    for (int nt = 0; nt < 4; ++nt) {
        const int j = nt * 16 + lr;  // feature column (= D's col for this lane)
        const unsigned swz = (((unsigned)j & 7u) << 4);
        const unsigned bh_base = (unsigned)j * 256u;            // hi plane
        const unsigned bl_base = 16384u + (unsigned)j * 256u;   // lo plane (16KB stride)
        f32x4 acc = {0.0f, 0.0f, 0.0f, 0.0f};
#pragma unroll
        for (int ks = 0; ks < 4; ++ks) {
            unsigned off = ((unsigned)kg << 4) + ((unsigned)ks << 6);
            short8v bh = *(const short8v*)(lds0 + ((bh_base + off) ^ swz));
            short8v bl = *(const short8v*)(lds0 + ((bl_base + off) ^ swz));
            acc = __builtin_amdgcn_mfma_f32_16x16x32_bf16(ah[ks], bh, acc, 0, 0, 0);
            acc = __builtin_amdgcn_mfma_f32_16x16x32_bf16(ah[ks], bl, acc, 0, 0, 0);
            acc = __builtin_amdgcn_mfma_f32_16x16x32_bf16(al[ks], bh, acc, 0, 0, 0);
        }
        const int rowb = base + kg * 4;  // D row = (lane>>4)*4 + reg
#pragma unroll
        for (int r = 0; r < 4; ++r) {
            int node = rowb + r;
            if (node < N_NODES) Oh[(size_t)node * OUT_F + j] = bf16_rne(acc[r]);
        }
    }
}

// FAT 1: blocks [0,BIN_BLOCKS) = counting-sort pass 1; rest = Q-GEMM (matQ).
// bin and qk are data-independent -> concurrent. 32KB LDS keeps bin blocks at
// ~4 blocks/CU. __launch_bounds__(256,2) pins VGPR budget (R10 spill lesson).
__global__ __launch_bounds__(256, 2) void fat_bin_qkq(const void* __restrict__ ei,
                                                      const int* __restrict__ eflag,
                                                      int* __restrict__ bcnt,
                                                      unsigned* __restrict__ binned,
                                                      const float* __restrict__ x,
                                                      const ushort* __restrict__ wh,
                                                      const ushort* __restrict__ wl,
                                                      ushort* __restrict__ Qh) {
    __shared__ __align__(16) char smem[32768];
    const int t = threadIdx.x;

    if (blockIdx.x < BIN_BLOCKS) {
        // ---- counting-sort pass 1 ----
        unsigned* recbuf = (unsigned*)smem;                  // 8 KB
        int* cnt = (int*)(smem + BIN_CHUNK * 4);             // 784 B
        int* gbase = (int*)(smem + BIN_CHUNK * 4 + 1024);    // 784 B
        const int sflag = *eflag;  // uniform broadcast load (L2-hot)
        for (int i = t; i < NBUK; i += 256) cnt[i] = 0;
        __syncthreads();

        const int e0 = blockIdx.x * BIN_CHUNK;
        const int nloc = min(BIN_CHUNK, N_EDGES - e0);
        for (int i = t; i < nloc; i += 256) {
            int e = e0 + i;
            int r, c;
            if (sflag) {
                const long long* p = (const long long*)ei;
                r = (int)p[e];
                c = (int)p[N_EDGES + e];
            } else {
                const int* p = (const int*)ei;
                r = p[e];
                c = p[N_EDGES + e];
            }
            unsigned rec = (unsigned)r | ((unsigned)c << 16);
            recbuf[i] = rec;
            atomicAdd(&cnt[c >> 8], 1);
        }
        __syncthreads();
        for (int i = t; i < NBUK; i += 256) {
            gbase[i] = atomicAdd(&bcnt[i], cnt[i]);
            cnt[i] = 0;
        }
        __syncthreads();
        for (int i = t; i < nloc; i += 256) {
            unsigned rec = recbuf[i];
            int b = rec >> 24;  // col>>8
            int lp = atomicAdd(&cnt[b], 1);
            int pos = gbase[b] + lp;
            if (pos >= BCAP) pos = BCAP - 1;  // unreachable; OOB guard
            binned[(size_t)b * BCAP + pos] = rec;
        }
        return;
    }

    qk_gemm_half(x, wh, wl, Qh, smem, blockIdx.x - BIN_BLOCKS, t);
}

// FAT 2: blocks [0,NBUK) = counting-sort pass 2 (bucket_build); rest = K-GEMM
// (matK). bucket and qk are data-independent -> concurrent.
__global__ __launch_bounds__(256, 2) void fat_bucket_qkk(const unsigned* __restrict__ binned,
                                                         const int* __restrict__ bcnt,
                                                         int* __restrict__ offs,
                                                         ushort* __restrict__ sorted_row,
                                                         const float* __restrict__ x,
                                                         const ushort* __restrict__ wh,
                                                         const ushort* __restrict__ wl,
                                                         ushort* __restrict__ Kh) {
    __shared__ __align__(16) char smem[32768];
    const int t = threadIdx.x;

    if (blockIdx.x < NBUK) {
        // ---- counting-sort pass 2: one block per bucket ----
        int* colcnt = (int*)smem;                // 1 KB
        int* colhead = (int*)(smem + 1024);      // 1 KB
        int* s = (int*)(smem + 2048);            // 1 KB
        ushort* image = (ushort*)(smem + 3072);  // 10 KB
        const int b = blockIdx.x;
        const int c0 = b << 8;
        const int cntb = bcnt[b];
        const unsigned* slab = binned + (size_t)b * BCAP;

        // baseb = sum(bcnt[0..b))
        s[t] = (t < b) ? bcnt[t] : 0;  // b <= 195 < 256
        __syncthreads();
        for (int off = 128; off > 0; off >>= 1) {
            if (t < off) s[t] += s[t + off];
            __syncthreads();
        }
        const int baseb = s[0];
        __syncthreads();  // s reused below

        colcnt[t] = 0;
        __syncthreads();
        for (int i = t; i < cntb; i += 256)
            atomicAdd(&colcnt[(slab[i] >> 16) & 0xFF], 1);
        __syncthreads();
        s[t] = colcnt[t];
        __syncthreads();
        for (int off = 1; off < 256; off <<= 1) {
            int u = (t >= off) ? s[t - off] : 0;
            __syncthreads();
            s[t] += u;
            __syncthreads();
        }
        const int excl = s[t] - colcnt[t];
        colhead[t] = excl;
        if (c0 + t < N_NODES) offs[c0 + t] = baseb + excl;
        __syncthreads();
        for (int i = t; i < cntb; i += 256) {
            unsigned rec = slab[i];
            int p = atomicAdd(&colhead[(rec >> 16) & 0xFF], 1);
            image[p] = (ushort)(rec & 0xFFFF);
        }
        __syncthreads();
        for (int i = t; i < cntb; i += 256)
            sorted_row[baseb + i] = image[i];
        return;
    }

    qk_gemm_half(x, wh + OUT_F * IN_F, wl + OUT_F * IN_F, Kh, smem,
                 blockIdx.x - NBUK, t);
}

// TWO waves per destination node (block = 4 waves = 2 nodes). Each wave has 4
// groups of 16 lanes; the 8 groups of a node's wave-pair stride the edge list
// by 8; each group runs the PROVEN 2-chain inner loop (stride 16). This
// halves the serial gather->use chain depth per group (deg/16 rounds vs
// deg/8) and doubles wave-level parallelism -- attacking the measured
// latency-bound regime (VALU floor ~4us vs ~24us observed). Wave partials
// merge via a tiny LDS buffer + one __syncthreads.
// NO max tracking (shift-invariance; logits tiny: sigma~0.33, max|alpha|~1.7,
// exp in [0.2,5.5] vs f32 ~1e38). log2(e)/8 folded into K load; exp2f native.
// N_NODES is even -> n = blockIdx*2 + (wave>>1) never exceeds N_NODES-1.
__global__ __launch_bounds__(256) void gat_node(const ushort* __restrict__ Qh,
                                                const ushort* __restrict__ Kh,
                                                const ushort* __restrict__ sorted_row,
                                                const int* __restrict__ offs,
                                                float* __restrict__ out) {
    __shared__ float part[2][16][5];  // [node-slot][gl][d,ox,oy,oz,ow]
    const int wave = threadIdx.x >> 6, lane = threadIdx.x & 63;
    const int ns = wave >> 1;             // node slot within block (0,1)
    const int h = wave & 1;               // half index within the node
    const int n = blockIdx.x * 2 + ns;
    const int g = lane >> 4, gl = lane & 15;
    const int start = offs[n], deg = offs[n + 1] - start;

    const float C = 1.44269504f * 0.125f;  // log2(e)/sqrt(64)
    const ushort4 kh = *(const ushort4*)(Kh + (size_t)n * OUT_F + gl * 4);
    const float kx = bf2f(kh.x) * C, ky = bf2f(kh.y) * C;
    const float kz = bf2f(kh.z) * C, kw = bf2f(kh.w) * C;

    float d0 = 0.0f, d1 = 0.0f;
    float4 o0 = {0.0f, 0.0f, 0.0f, 0.0f};
    float4 o1 = {0.0f, 0.0f, 0.0f, 0.0f};

    int i = h * 4 + g;  // this group's residue mod 8
    for (; i + 8 < deg; i += 16) {
        int r0 = (int)sorted_row[start + i];
        int r1 = (int)sorted_row[start + i + 8];
        ushort4 qh0 = *(const ushort4*)(Qh + (size_t)r0 * OUT_F + gl * 4);
        ushort4 qh1 = *(const ushort4*)(Qh + (size_t)r1 * OUT_F + gl * 4);
        float q0x = bf2f(qh0.x), q0y = bf2f(qh0.y), q0z = bf2f(qh0.z), q0w = bf2f(qh0.w);
        float q1x = bf2f(qh1.x), q1y = bf2f(qh1.y), q1z = bf2f(qh1.z), q1w = bf2f(qh1.w);
        float p0 = q0x * kx + q0y * ky + q0z * kz + q0w * kw;
        float p1 = q1x * kx + q1y * ky + q1z * kz + q1w * kw;
        p0 += __shfl_xor(p0, 1);
        p1 += __shfl_xor(p1, 1);
        p0 += __shfl_xor(p0, 2);
        p1 += __shfl_xor(p1, 2);
        p0 += __shfl_xor(p0, 4);
        p1 += __shfl_xor(p1, 4);
        p0 += __shfl_xor(p0, 8);
        p1 += __shfl_xor(p1, 8);
        float e0 = exp2f(p0);
        float e1 = exp2f(p1);
        d0 += e0;
        d1 += e1;
        o0.x += e0 * q0x;
        o0.y += e0 * q0y;
        o0.z += e0 * q0z;
        o0.w += e0 * q0w;
        o1.x += e1 * q1x;
        o1.y += e1 * q1y;
        o1.z += e1 * q1z;
        o1.w += e1 * q1w;
    }
    if (i < deg) {  // tail: at most one leftover edge for this group
        int r0 = (int)sorted_row[start + i];
        ushort4 qh0 = *(const ushort4*)(Qh + (size_t)r0 * OUT_F + gl * 4);
        float q0x = bf2f(qh0.x), q0y = bf2f(qh0.y), q0z = bf2f(qh0.z), q0w = bf2f(qh0.w);
        float p0 = q0x * kx + q0y * ky + q0z * kz + q0w * kw;
        p0 += __shfl_xor(p0, 1);
        p0 += __shfl_xor(p0, 2);
        p0 += __shfl_xor(p0, 4);
        p0 += __shfl_xor(p0, 8);
        float e0 = exp2f(p0);
        d0 += e0;
        o0.x += e0 * q0x;
        o0.y += e0 * q0y;
        o0.z += e0 * q0z;
        o0.w += e0 * q0w;
    }

    // merge chain 1 into chain 0 (plain adds)
    d0 += d1;
    o0.x += o1.x;
    o0.y += o1.y;
    o0.z += o1.z;
    o0.w += o1.w;

    // cross-group merge within the wave (plain shfl adds, xor 16 then 32)
#pragma unroll
    for (int off = 16; off <= 32; off <<= 1) {
        d0 += __shfl_xor(d0, off);
        o0.x += __shfl_xor(o0.x, off);
        o0.y += __shfl_xor(o0.y, off);
        o0.z += __shfl_xor(o0.z, off);
        o0.w += __shfl_xor(o0.w, off);
    }

    // cross-wave merge: half 1 publishes, half 0 combines and writes.
    if (h == 1 && g == 0) {
        part[ns][gl][0] = d0;
        part[ns][gl][1] = o0.x;
        part[ns][gl][2] = o0.y;
        part[ns][gl][3] = o0.z;
        part[ns][gl][4] = o0.w;
    }
    __syncthreads();
    if (h == 0 && g == 0) {
        d0 += part[ns][gl][0];
        o0.x += part[ns][gl][1];
        o0.y += part[ns][gl][2];
        o0.z += part[ns][gl][3];
        o0.w += part[ns][gl][4];
        float inv = 1.0f / (d0 + 1e-16f);
        float4 r = {o0.x * inv, o0.y * inv, o0.z * inv, o0.w * inv};
        *(float4*)(out + (size_t)n * OUT_F + gl * 4) = r;
    }
}

extern "C" void kernel_launch(void* const* d_in, const int* in_sizes, int n_in,
                              void* d_out, int out_size, void* d_ws, size_t ws_size,
                              hipStream_t stream) {
    const float* x = (const float*)d_in[0];
    const void* ei = d_in[1];
    const float* Wq = (const float*)d_in[2];
    const float* Wk = (const float*)d_in[3];
    float* out = (float*)d_out;

    char* ws = (char*)d_ws;
    ushort* Qh = (ushort*)ws;         ws += (size_t)N_NODES * OUT_F * 2;
    ushort* Kh = (ushort*)ws;         ws += (size_t)N_NODES * OUT_F * 2;
    unsigned* binned = (unsigned*)ws; ws += (size_t)NBUK * BCAP * 4;
    ushort* sorted_row = (ushort*)ws; ws += (size_t)N_EDGES * 2;
    ushort* wh = (ushort*)ws;         ws += (size_t)2 * OUT_F * IN_F * 2;
    ushort* wl = (ushort*)ws;         ws += (size_t)2 * OUT_F * IN_F * 2;
    ws = (char*)(((size_t)ws + 255) & ~(size_t)255);
    int* bcnt = (int*)ws;             ws += (size_t)NBUK * 4;
    int* offs = (int*)ws;             ws += (size_t)(N_NODES + 1) * 4;
    int* eflag = (int*)ws;            ws += 256;

    // wsplit zeroes bcnt, seeds offs[N_NODES], computes eflag (same-stream order).
    wsplit<<<(2 * OUT_F * IN_F + 255) / 256, 256, 0, stream>>>(Wq, Wk, (const int*)ei,
                                                               wh, wl, bcnt, offs, eflag);
    fat_bin_qkq<<<BIN_BLOCKS + QK_BLOCKS, 256, 0, stream>>>(ei, eflag, bcnt, binned,
                                                            x, wh, wl, Qh);
    fat_bucket_qkk<<<NBUK + QK_BLOCKS, 256, 0, stream>>>(binned, bcnt, offs, sorted_row,
                                                         x, wh, wl, Kh);
    gat_node<<<N_NODES / 2, 256, 0, stream>>>(Qh, Kh, sorted_row, offs, out);
}

// Round 20
// 73.597 us; speedup vs baseline: 1.1079x; 1.1079x over previous
//
#include <hip/hip_runtime.h>
#include <math.h>

#define N_NODES 50000
#define N_EDGES 800000
#define IN_F 128
#define OUT_F 64

#define NBUK 196        // col>>8 buckets (ceil(50000/256))
#define BCAP 5120       // slab capacity per bucket (mean 4082, sigma 64 -> +16 sigma)
#define BIN_CHUNK 2048  // edges per bin block
#define BIN_BLOCKS ((N_EDGES + BIN_CHUNK - 1) / BIN_CHUNK)  // 391
#define QK_NB 64        // nodes per block in the qk path
#define QK_BLOCKS ((N_NODES + QK_NB - 1) / QK_NB)           // 782

typedef __attribute__((ext_vector_type(8))) short short8v;  // 8 bf16 (4 VGPR)
typedef __attribute__((ext_vector_type(4))) float f32x4;    // MFMA C/D

// ---- RNE f32 -> bf16 helpers (no NaN/inf in this data) ----
__device__ __forceinline__ unsigned short bf16_rne(float f) {
    unsigned u = __float_as_uint(f);
    return (unsigned short)((u + 0x7FFFu + ((u >> 16) & 1u)) >> 16);
}
__device__ __forceinline__ void split2(float f, unsigned short& h, unsigned short& l) {
    h = bf16_rne(f);
    float fh = __uint_as_float(((unsigned)h) << 16);
    l = bf16_rne(f - fh);
}
__device__ __forceinline__ float bf2f(ushort h) {
    return __uint_as_float(((unsigned)h) << 16);
}

// Tiny init: zero bcnt, seed offs[N_NODES], compute the int64-vs-int32
// edge-layout flag. One block. (W splitting moved in-register into the qk
// halves -- wh/wl buffers and the old wsplit stage are gone.)
__global__ __launch_bounds__(256) void init_kernel(const int* __restrict__ ei,
                                                   int* __restrict__ bcnt,
                                                   int* __restrict__ offs,
                                                   int* __restrict__ eflag) {
    if (threadIdx.x < NBUK) bcnt[threadIdx.x] = 0;
    if (threadIdx.x == 0) {
        offs[N_NODES] = N_EDGES;
        int allz = 1;
        for (int k = 0; k < 32; ++k)
            if (ei[2 * k + 1] != 0) allz = 0;
        *eflag = allz;  // 1 => int64 layout (odd words of int64 values < 2^31 are 0)
    }
}

// One matrix's worth of the split-bf16 MFMA GEMM (D = xh*wh + xh*wl + xl*wh,
// xl*wl ~ 2^-18 dropped). Stages the matrix's hi/lo planes (32KB) in LDS with
// the XOR swizzle byte^=((j&7)<<4) (wave's 64 b128 reads tile all 32 banks).
// W is split from f32 IN-REGISTER during staging (reads the same 32KB, saves
// the separate wsplit pass). LDS-staged proven vs direct-global in R13/R14
// A/B (+15us L1 thrash).
__device__ __forceinline__ void qk_gemm_half(const float* __restrict__ x,
                                             const float* __restrict__ W,
                                             ushort* __restrict__ Oh,
                                             char* lds0, int qbid, int t) {
    // stage: 1024 source b256-f32 units -> hi plane + lo plane (swizzled)
    for (int v = t; v < 1024; v += 256) {
        int j = v >> 4, kb = v & 15;
        const float* src = W + (j << 7) + (kb << 3);
        float4 a0 = *(const float4*)src;
        float4 a1 = *(const float4*)(src + 4);
        float vals[8] = {a0.x, a0.y, a0.z, a0.w, a1.x, a1.y, a1.z, a1.w};
        short8v hv, lv;
#pragma unroll
        for (int jj = 0; jj < 8; ++jj) {
            unsigned short h, lo;
            split2(vals[jj], h, lo);
            hv[jj] = (short)h;
            lv[jj] = (short)lo;
        }
        unsigned byte = ((unsigned)v * 16u) ^ (((unsigned)j & 7u) << 4);
        *(short8v*)(lds0 + byte) = hv;             // hi plane [0, 16KB)
        *(short8v*)(lds0 + 16384u + byte) = lv;    // lo plane [16KB, 32KB)
    }

    const int w = t >> 6, l = t & 63;
    const int base = qbid * QK_NB + w * 16;
    const int lr = l & 15, kg = l >> 4;

    int nodeA = base + lr;
    if (nodeA >= N_NODES) nodeA = N_NODES - 1;  // clamped load, stores guarded
    const float* xp = x + (size_t)nodeA * IN_F + kg * 8;

    short8v ah[4], al[4];
#pragma unroll
    for (int ks = 0; ks < 4; ++ks) {
        float4 a0 = *(const float4*)(xp + ks * 32);
        float4 a1 = *(const float4*)(xp + ks * 32 + 4);
        float v[8] = {a0.x, a0.y, a0.z, a0.w, a1.x, a1.y, a1.z, a1.w};
#pragma unroll
        for (int jj = 0; jj < 8; ++jj) {
            unsigned short h, lo;
            split2(v[jj], h, lo);
            ah[ks][jj] = (short)h;
            al[ks][jj] = (short)lo;
        }
    }

    __syncthreads();

#pragma unroll
    for (int nt = 0; nt < 4; ++nt) {
        const int j = nt * 16 + lr;  // feature column (= D's col for this lane)
        const unsigned swz = (((unsigned)j & 7u) << 4);
        const unsigned bh_base = (unsigned)j * 256u;            // hi plane
        const unsigned bl_base = 16384u + (unsigned)j * 256u;   // lo plane
        f32x4 acc = {0.0f, 0.0f, 0.0f, 0.0f};
#pragma unroll
        for (int ks = 0; ks < 4; ++ks) {
            unsigned off = ((unsigned)kg << 4) + ((unsigned)ks << 6);
            short8v bh = *(const short8v*)(lds0 + ((bh_base + off) ^ swz));
            short8v bl = *(const short8v*)(lds0 + ((bl_base + off) ^ swz));
            acc = __builtin_amdgcn_mfma_f32_16x16x32_bf16(ah[ks], bh, acc, 0, 0, 0);
            acc = __builtin_amdgcn_mfma_f32_16x16x32_bf16(ah[ks], bl, acc, 0, 0, 0);
            acc = __builtin_amdgcn_mfma_f32_16x16x32_bf16(al[ks], bh, acc, 0, 0, 0);
        }
        const int rowb = base + kg * 4;  // D row = (lane>>4)*4 + reg
#pragma unroll
        for (int r = 0; r < 4; ++r) {
            int node = rowb + r;
            if (node < N_NODES) Oh[(size_t)node * OUT_F + j] = bf16_rne(acc[r]);
        }
    }
}

// FAT 1: blocks [0,BIN_BLOCKS) = counting-sort pass 1; rest = Q-GEMM (matQ).
// bin and qk are data-independent -> concurrent. 32KB LDS keeps bin blocks at
// ~4 blocks/CU. __launch_bounds__(256,2) pins VGPR budget (R10 spill lesson).
__global__ __launch_bounds__(256, 2) void fat_bin_qkq(const void* __restrict__ ei,
                                                      const int* __restrict__ eflag,
                                                      int* __restrict__ bcnt,
                                                      unsigned* __restrict__ binned,
                                                      const float* __restrict__ x,
                                                      const float* __restrict__ Wq,
                                                      ushort* __restrict__ Qh) {
    __shared__ __align__(16) char smem[32768];
    const int t = threadIdx.x;

    if (blockIdx.x < BIN_BLOCKS) {
        // ---- counting-sort pass 1 ----
        unsigned* recbuf = (unsigned*)smem;                  // 8 KB
        int* cnt = (int*)(smem + BIN_CHUNK * 4);             // 784 B
        int* gbase = (int*)(smem + BIN_CHUNK * 4 + 1024);    // 784 B
        const int sflag = *eflag;  // uniform broadcast load (L2-hot)
        for (int i = t; i < NBUK; i += 256) cnt[i] = 0;
        __syncthreads();

        const int e0 = blockIdx.x * BIN_CHUNK;
        const int nloc = min(BIN_CHUNK, N_EDGES - e0);
        for (int i = t; i < nloc; i += 256) {
            int e = e0 + i;
            int r, c;
            if (sflag) {
                const long long* p = (const long long*)ei;
                r = (int)p[e];
                c = (int)p[N_EDGES + e];
            } else {
                const int* p = (const int*)ei;
                r = p[e];
                c = p[N_EDGES + e];
            }
            unsigned rec = (unsigned)r | ((unsigned)c << 16);
            recbuf[i] = rec;
            atomicAdd(&cnt[c >> 8], 1);
        }
        __syncthreads();
        for (int i = t; i < NBUK; i += 256) {
            gbase[i] = atomicAdd(&bcnt[i], cnt[i]);
            cnt[i] = 0;
        }
        __syncthreads();
        for (int i = t; i < nloc; i += 256) {
            unsigned rec = recbuf[i];
            int b = rec >> 24;  // col>>8
            int lp = atomicAdd(&cnt[b], 1);
            int pos = gbase[b] + lp;
            if (pos >= BCAP) pos = BCAP - 1;  // unreachable; OOB guard
            binned[(size_t)b * BCAP + pos] = rec;
        }
        return;
    }

    qk_gemm_half(x, Wq, Qh, smem, blockIdx.x - BIN_BLOCKS, t);
}

// FAT 2: blocks [0,NBUK) = counting-sort pass 2 (bucket_build); rest = K-GEMM
// (matK). bucket and qk are data-independent -> concurrent.
__global__ __launch_bounds__(256, 2) void fat_bucket_qkk(const unsigned* __restrict__ binned,
                                                         const int* __restrict__ bcnt,
                                                         int* __restrict__ offs,
                                                         ushort* __restrict__ sorted_row,
                                                         const float* __restrict__ x,
                                                         const float* __restrict__ Wk,
                                                         ushort* __restrict__ Kh) {
    __shared__ __align__(16) char smem[32768];
    const int t = threadIdx.x;

    if (blockIdx.x < NBUK) {
        // ---- counting-sort pass 2: one block per bucket ----
        int* colcnt = (int*)smem;                // 1 KB
        int* colhead = (int*)(smem + 1024);      // 1 KB
        int* s = (int*)(smem + 2048);            // 1 KB
        ushort* image = (ushort*)(smem + 3072);  // 10 KB
        const int b = blockIdx.x;
        const int c0 = b << 8;
        const int cntb = bcnt[b];
        const unsigned* slab = binned + (size_t)b * BCAP;

        // baseb = sum(bcnt[0..b))
        s[t] = (t < b) ? bcnt[t] : 0;  // b <= 195 < 256
        __syncthreads();
        for (int off = 128; off > 0; off >>= 1) {
            if (t < off) s[t] += s[t + off];
            __syncthreads();
        }
        const int baseb = s[0];
        __syncthreads();  // s reused below

        colcnt[t] = 0;
        __syncthreads();
        for (int i = t; i < cntb; i += 256)
            atomicAdd(&colcnt[(slab[i] >> 16) & 0xFF], 1);
        __syncthreads();
        s[t] = colcnt[t];
        __syncthreads();
        for (int off = 1; off < 256; off <<= 1) {
            int u = (t >= off) ? s[t - off] : 0;
            __syncthreads();
            s[t] += u;
            __syncthreads();
        }
        const int excl = s[t] - colcnt[t];
        colhead[t] = excl;
        if (c0 + t < N_NODES) offs[c0 + t] = baseb + excl;
        __syncthreads();
        for (int i = t; i < cntb; i += 256) {
            unsigned rec = slab[i];
            int p = atomicAdd(&colhead[(rec >> 16) & 0xFF], 1);
            image[p] = (ushort)(rec & 0xFFFF);
        }
        __syncthreads();
        for (int i = t; i < cntb; i += 256)
            sorted_row[baseb + i] = image[i];
        return;
    }

    qk_gemm_half(x, Wk, Kh, smem, blockIdx.x - NBUK, t);
}

// One wave per destination node; 4 groups of 16 lanes; TWO independent
// accumulator chains per group (stride 8) -- the measured optimum on both
// axes: chains/group (2 beats 1 and 4, R11/R12/R18) and waves/node (1 beats
// 2, R19). NO max tracking (shift-invariance; logits tiny: sigma~0.33,
// max|alpha|~1.7, exp in [0.2,5.5] vs f32 ~1e38). log2(e)/8 folded into the
// K load; exp2f = native v_exp_f32; merges are plain adds.
__global__ __launch_bounds__(256) void gat_node(const ushort* __restrict__ Qh,
                                                const ushort* __restrict__ Kh,
                                                const ushort* __restrict__ sorted_row,
                                                const int* __restrict__ offs,
                                                float* __restrict__ out) {
    const int wave = threadIdx.x >> 6, lane = threadIdx.x & 63;
    const int n = blockIdx.x * 4 + wave;
    if (n >= N_NODES) return;
    const int g = lane >> 4, gl = lane & 15;
    const int start = offs[n], deg = offs[n + 1] - start;

    const float C = 1.44269504f * 0.125f;  // log2(e)/sqrt(64)
    const ushort4 kh = *(const ushort4*)(Kh + (size_t)n * OUT_F + gl * 4);
    const float kx = bf2f(kh.x) * C, ky = bf2f(kh.y) * C;
    const float kz = bf2f(kh.z) * C, kw = bf2f(kh.w) * C;

    float d0 = 0.0f, d1 = 0.0f;
    float4 o0 = {0.0f, 0.0f, 0.0f, 0.0f};
    float4 o1 = {0.0f, 0.0f, 0.0f, 0.0f};

    int i = g;
    for (; i + 4 < deg; i += 8) {
        int r0 = (int)sorted_row[start + i];
        int r1 = (int)sorted_row[start + i + 4];
        ushort4 qh0 = *(const ushort4*)(Qh + (size_t)r0 * OUT_F + gl * 4);
        ushort4 qh1 = *(const ushort4*)(Qh + (size_t)r1 * OUT_F + gl * 4);
        float q0x = bf2f(qh0.x), q0y = bf2f(qh0.y), q0z = bf2f(qh0.z), q0w = bf2f(qh0.w);
        float q1x = bf2f(qh1.x), q1y = bf2f(qh1.y), q1z = bf2f(qh1.z), q1w = bf2f(qh1.w);
        float p0 = q0x * kx + q0y * ky + q0z * kz + q0w * kw;
        float p1 = q1x * kx + q1y * ky + q1z * kz + q1w * kw;
        p0 += __shfl_xor(p0, 1);
        p1 += __shfl_xor(p1, 1);
        p0 += __shfl_xor(p0, 2);
        p1 += __shfl_xor(p1, 2);
        p0 += __shfl_xor(p0, 4);
        p1 += __shfl_xor(p1, 4);
        p0 += __shfl_xor(p0, 8);
        p1 += __shfl_xor(p1, 8);
        float e0 = exp2f(p0);
        float e1 = exp2f(p1);
        d0 += e0;
        d1 += e1;
        o0.x += e0 * q0x;
        o0.y += e0 * q0y;
        o0.z += e0 * q0z;
        o0.w += e0 * q0w;
        o1.x += e1 * q1x;
        o1.y += e1 * q1y;
        o1.z += e1 * q1z;
        o1.w += e1 * q1w;
    }
    if (i < deg) {  // tail: at most one leftover group-edge
        int r0 = (int)sorted_row[start + i];
        ushort4 qh0 = *(const ushort4*)(Qh + (size_t)r0 * OUT_F + gl * 4);
        float q0x = bf2f(qh0.x), q0y = bf2f(qh0.y), q0z = bf2f(qh0.z), q0w = bf2f(qh0.w);
        float p0 = q0x * kx + q0y * ky + q0z * kz + q0w * kw;
        p0 += __shfl_xor(p0, 1);
        p0 += __shfl_xor(p0, 2);
        p0 += __shfl_xor(p0, 4);
        p0 += __shfl_xor(p0, 8);
        float e0 = exp2f(p0);
        d0 += e0;
        o0.x += e0 * q0x;
        o0.y += e0 * q0y;
        o0.z += e0 * q0z;
        o0.w += e0 * q0w;
    }

    // merge chain 1 into chain 0 (plain adds)
    d0 += d1;
    o0.x += o1.x;
    o0.y += o1.y;
    o0.z += o1.z;
    o0.w += o1.w;

    // cross-group merge (plain shfl adds, xor 16 then 32)
#pragma unroll
    for (int off = 16; off <= 32; off <<= 1) {
        d0 += __shfl_xor(d0, off);
        o0.x += __shfl_xor(o0.x, off);
        o0.y += __shfl_xor(o0.y, off);
        o0.z += __shfl_xor(o0.z, off);
        o0.w += __shfl_xor(o0.w, off);
    }

    if (g == 0) {
        float inv = 1.0f / (d0 + 1e-16f);
        float4 r = {o0.x * inv, o0.y * inv, o0.z * inv, o0.w * inv};
        *(float4*)(out + (size_t)n * OUT_F + gl * 4) = r;
    }
}

extern "C" void kernel_launch(void* const* d_in, const int* in_sizes, int n_in,
                              void* d_out, int out_size, void* d_ws, size_t ws_size,
                              hipStream_t stream) {
    const float* x = (const float*)d_in[0];
    const void* ei = d_in[1];
    const float* Wq = (const float*)d_in[2];
    const float* Wk = (const float*)d_in[3];
    float* out = (float*)d_out;

    char* ws = (char*)d_ws;
    ushort* Qh = (ushort*)ws;         ws += (size_t)N_NODES * OUT_F * 2;
    ushort* Kh = (ushort*)ws;         ws += (size_t)N_NODES * OUT_F * 2;
    unsigned* binned = (unsigned*)ws; ws += (size_t)NBUK * BCAP * 4;
    ushort* sorted_row = (ushort*)ws; ws += (size_t)N_EDGES * 2;
    ws = (char*)(((size_t)ws + 255) & ~(size_t)255);
    int* bcnt = (int*)ws;             ws += (size_t)NBUK * 4;
    int* offs = (int*)ws;             ws += (size_t)(N_NODES + 1) * 4;
    int* eflag = (int*)ws;            ws += 256;

    init_kernel<<<1, 256, 0, stream>>>((const int*)ei, bcnt, offs, eflag);
    fat_bin_qkq<<<BIN_BLOCKS + QK_BLOCKS, 256, 0, stream>>>(ei, eflag, bcnt, binned,
                                                            x, Wq, Qh);
    fat_bucket_qkk<<<NBUK + QK_BLOCKS, 256, 0, stream>>>(binned, bcnt, offs, sorted_row,
                                                         x, Wk, Kh);
    gat_node<<<(N_NODES + 3) / 4, 256, 0, stream>>>(Qh, Kh, sorted_row, offs, out);
}